// Round 4
// baseline (488.033 us; speedup 1.0000x reference)
//
#include <hip/hip_runtime.h>
#include <hip/hip_bf16.h>

typedef unsigned short u16;
typedef __bf16 bf16x8 __attribute__((ext_vector_type(8)));
typedef float  f32x4  __attribute__((ext_vector_type(4)));

__device__ __forceinline__ unsigned pk2(float a, float b) {
    __hip_bfloat162 h = __float22bfloat162_rn(make_float2(a, b));
    unsigned u; __builtin_memcpy(&u, &h, 4);
    return u;   // low 16 = bf16(a), high 16 = bf16(b)
}
__device__ __forceinline__ u16 f2b1(float f) { return (u16)(pk2(f, f) & 0xFFFFu); }

#define MFMA __builtin_amdgcn_mfma_f32_16x16x32_bf16

// ---------------------------------------------------------------------------
// prep: ppK[r][j] = (pos_table[r].W_pos_w[j,128:256] + W_pos_b[j]) * 2*log2(e)
//       wb1[j][k] = bf16(W_pos_w[j][k])  (k<128, GEMM1 B operand, row-major)
//       wb2[j][k] = bf16(W2[j][k])       (GEMM2 B operand, row-major)
// ---------------------------------------------------------------------------
__global__ __launch_bounds__(128) void prep_kernel(
    const float* __restrict__ pos_table, const float* __restrict__ Wpw,
    const float* __restrict__ Wpb, const float* __restrict__ W2,
    float* __restrict__ ppK, u16* __restrict__ wb1, u16* __restrict__ wb2)
{
    const int b = blockIdx.x, t = threadIdx.x;
    if (b < 65) {
        const float4* pr = (const float4*)(pos_table + b * 128);
        const float4* wr = (const float4*)(Wpw + t * 256 + 128);
        float acc = Wpb[t];
        #pragma unroll
        for (int k = 0; k < 32; ++k) {
            const float4 p = pr[k], wv = wr[k];
            acc += p.x * wv.x + p.y * wv.y + p.z * wv.z + p.w * wv.w;
        }
        ppK[b * 128 + t] = acc * 2.885390081777927f;   // pre-scaled for exp2
    } else {
        const int j = b - 65;                          // 0..127
        wb1[j * 128 + t] = f2b1(Wpw[j * 256 + t]);
        wb2[j * 128 + t] = f2b1(W2[j * 128 + t]);
    }
}

// ---------------------------------------------------------------------------
// fused: one block = TWO sessions (128 token rows), 512 threads = 8 waves.
// wave w owns rows 16w..16w+15 (session w>>2). Same 73 KB LDS as the 256-thr
// version -> still 2 blocks/CU, but 16 waves/CU instead of 8 (latency hiding).
// wb2 is prefetched into registers in phase 1 so the restage between GEMMs
// has no global-load latency on the barrier-to-barrier critical path.
// ---------------------------------------------------------------------------
__global__ __launch_bounds__(512, 4) void fused_kernel(
    const float* __restrict__ hidden, const int* __restrict__ rpos,
    const float* __restrict__ W1, const float* __restrict__ W1b,
    const float* __restrict__ W2b, const float* __restrict__ qw,
    const float* __restrict__ qb, const float* __restrict__ ppK,
    const u16* __restrict__ wb1g, const u16* __restrict__ wb2g,
    float* __restrict__ out)
{
    // 128 rows x 136 bf16 (pad +8: 272B row stride keeps 16B align, 2-way-free)
    __shared__ __align__(16) u16 hbf[128 * 136];    // 34816 B (hidden -> ph)
    __shared__ __align__(16) u16 wb[128 * 136];     // 34816 B (wb1 -> wb2)
    __shared__ __align__(16) float scratch[512];    // meanv[2][128] -> partials
    __shared__ float g1s[256];                      // [2][128]
    __shared__ float qws[128];
    __shared__ float alphas[128];
    __shared__ int   rps[128];                      // total 73216 B

    const int tid = threadIdx.x;
    const int blk = blockIdx.x;
    const int w = tid >> 6;                 // wave 0..7, rows 16w..16w+15
    const int l = tid & 63;
    const int c = l & 15;                   // MFMA A-row / B-row / D-col
    const int g = l >> 4;                   // quad
    const int R = 16 * w;
    const float* hsrc = hidden + (size_t)blk * (128 * 128);

    // ---- phase 0: zero mean accumulators, stage small vectors
    scratch[tid] = 0.f;
    if (tid < 128) { rps[tid] = rpos[blk * 128 + tid]; qws[tid] = qw[tid]; }
    __syncthreads();

    // ---- phase 1: hidden -> bf16 LDS + fp32 column sums; wb1 -> LDS;
    //      wb2 -> registers (prefetch).
    uint4 wreg[4];
    {
        float4 ms0 = {0.f, 0.f, 0.f, 0.f}, ms1 = {0.f, 0.f, 0.f, 0.f};
        #pragma unroll
        for (int i = 0; i < 8; ++i) {
            const int i4 = tid + i * 512;                 // float4 idx 0..4095
            const float4 v = ((const float4*)hsrc)[i4];
            const int row = i4 >> 5, col = (i4 * 4) & 127;
            uint2 st; st.x = pk2(v.x, v.y); st.y = pk2(v.z, v.w);
            *(uint2*)&hbf[row * 136 + col] = st;
            if (i < 4) { ms0.x += v.x; ms0.y += v.y; ms0.z += v.z; ms0.w += v.w; }
            else       { ms1.x += v.x; ms1.y += v.y; ms1.z += v.z; ms1.w += v.w; }
        }
        // lanes l and l+32 hold the same column group -> combine, then atomics
        ms0.x += __shfl_xor(ms0.x, 32, 64); ms0.y += __shfl_xor(ms0.y, 32, 64);
        ms0.z += __shfl_xor(ms0.z, 32, 64); ms0.w += __shfl_xor(ms0.w, 32, 64);
        ms1.x += __shfl_xor(ms1.x, 32, 64); ms1.y += __shfl_xor(ms1.y, 32, 64);
        ms1.z += __shfl_xor(ms1.z, 32, 64); ms1.w += __shfl_xor(ms1.w, 32, 64);
        if (l < 32) {
            const int mc = 4 * l;
            atomicAdd(&scratch[mc],           ms0.x); atomicAdd(&scratch[mc + 1],       ms0.y);
            atomicAdd(&scratch[mc + 2],       ms0.z); atomicAdd(&scratch[mc + 3],       ms0.w);
            atomicAdd(&scratch[128 + mc],     ms1.x); atomicAdd(&scratch[128 + mc + 1], ms1.y);
            atomicAdd(&scratch[128 + mc + 2], ms1.z); atomicAdd(&scratch[128 + mc + 3], ms1.w);
        }
    }
    #pragma unroll
    for (int i = 0; i < 4; ++i) {
        const int ch = tid + i * 512;                     // 0..2047 chunks of 8
        const int row = ch >> 4, col = (ch * 8) & 127;
        *(uint4*)&wb[row * 136 + col] = ((const uint4*)wb1g)[ch];
        wreg[i] = ((const uint4*)wb2g)[ch];               // prefetch W2
    }
    __syncthreads();

    // ---- g1[s][col] = mean[s].W1[col]/64 + W1_b + W2_b  (waves 0-3;
    //      waves 4-7 run ahead into GEMM1; visible at post-GEMM1 barrier)
    if (tid < 256) {
        const int col = tid & 127, s = tid >> 7;
        const float4* wr = (const float4*)(W1 + col * 128);
        const float4* mv = (const float4*)(scratch + s * 128);
        float acc = 0.f;
        #pragma unroll 8
        for (int k4 = 0; k4 < 32; ++k4) {
            const float4 wv = wr[k4], m4 = mv[k4];
            acc += m4.x * wv.x + m4.y * wv.y + m4.z * wv.z + m4.w * wv.w;
        }
        g1s[tid] = W1b[col] + W2b[col] + acc * (1.f / 64.f);
    }

    // ---- GEMM1: ph = tanh(hidden @ Wpa^T + pp)   M=16/wave, N=128, K=128
    bf16x8 af[4];
    #pragma unroll
    for (int kk = 0; kk < 4; ++kk)
        af[kk] = *(const bf16x8*)&hbf[(R + c) * 136 + kk * 32 + g * 8];
    f32x4 acc1[8] = {};
    #pragma unroll
    for (int n = 0; n < 8; ++n) {
        #pragma unroll
        for (int kk = 0; kk < 4; ++kk) {
            const bf16x8 bfr = *(const bf16x8*)&wb[(16 * n + c) * 136 + kk * 32 + g * 8];
            acc1[n] = MFMA(af[kk], bfr, acc1[n], 0, 0, 0);
        }
    }
    {
        const float K2 = 2.885390081777927f;        // 2*log2(e)
        const float* pkp[4];
        #pragma unroll
        for (int r = 0; r < 4; ++r)
            pkp[r] = ppK + rps[R + 4 * g + r] * 128 + c;
        #pragma unroll
        for (int n = 0; n < 8; ++n)
            #pragma unroll
            for (int r = 0; r < 4; ++r) {
                const float arg = fmaf(acc1[n][r], K2, pkp[r][16 * n]);
                const float e2 = __builtin_amdgcn_exp2f(arg);
                const float rc = __builtin_amdgcn_rcpf(e2 + 1.f);
                const float th = fmaf(-2.f, rc, 1.f);       // tanh
                hbf[(R + 4 * g + r) * 136 + 16 * n + c] = f2b1(th);  // own rows
            }
    }
    __syncthreads();   // wb1 B-reads done; ph committed; g1s visible

    // ---- GEMM2 A-frags (ph), then restage wb <- wb2 from registers
    bf16x8 af2[4];
    #pragma unroll
    for (int kk = 0; kk < 4; ++kk)
        af2[kk] = *(const bf16x8*)&hbf[(R + c) * 136 + kk * 32 + g * 8];
    #pragma unroll
    for (int i = 0; i < 4; ++i) {
        const int ch = tid + i * 512;
        const int row = ch >> 4, col = (ch * 8) & 127;
        *(uint4*)&wb[row * 136 + col] = wreg[i];
    }
    __syncthreads();

    // ---- GEMM2: gate = sigmoid(g1 + ph @ W2^T); alpha = gate.qw + qb
    f32x4 acc2[8] = {};
    #pragma unroll
    for (int n = 0; n < 8; ++n) {
        #pragma unroll
        for (int kk = 0; kk < 4; ++kk) {
            const bf16x8 bfr = *(const bf16x8*)&wb[(16 * n + c) * 136 + kk * 32 + g * 8];
            acc2[n] = MFMA(af2[kk], bfr, acc2[n], 0, 0, 0);
        }
    }
    {
        const float K1 = 1.4426950408889634f;       // log2(e)
        const int sw = w >> 2;                      // wave's session
        float garr[8], qarr[8];
        #pragma unroll
        for (int n = 0; n < 8; ++n) {
            garr[n] = -K1 * g1s[sw * 128 + 16 * n + c];
            qarr[n] = qws[16 * n + c];
        }
        float prt[4] = {};
        #pragma unroll
        for (int n = 0; n < 8; ++n)
            #pragma unroll
            for (int r = 0; r < 4; ++r) {
                const float arg = fmaf(acc2[n][r], -K1, garr[n]);
                const float e2 = __builtin_amdgcn_exp2f(arg);
                const float rc = __builtin_amdgcn_rcpf(e2 + 1.f);   // sigmoid
                prt[r] = fmaf(rc, qarr[n], prt[r]);
            }
        #pragma unroll
        for (int msk = 1; msk <= 8; msk <<= 1)
            #pragma unroll
            for (int r = 0; r < 4; ++r)
                prt[r] += __shfl_xor(prt[r], msk, 64);
        if (c == 0) {
            const float qbv = qb[0];
            #pragma unroll
            for (int r = 0; r < 4; ++r)
                alphas[R + 4 * g + r] = prt[r] + qbv;
        }
    }
    __syncthreads();

    // ---- out[s] = sum_t alpha_t * hidden[t]  (fp32 global, L2/L3-hot)
    // thread = (p = sess*2+half, column h); 32 tokens each; combine via LDS
    {
        const int h = tid & 127, p = tid >> 7;
        const int sess = p >> 1, half = p & 1;
        const float* hs = hsrc + (sess * 64 + half * 32) * 128 + h;
        const float* av = alphas + sess * 64 + half * 32;
        float accf = 0.f;
        #pragma unroll 8
        for (int t = 0; t < 32; ++t)
            accf = fmaf(av[t], hs[t * 128], accf);
        scratch[half * 256 + sess * 128 + h] = accf;
    }
    __syncthreads();
    if (tid < 256)
        out[(size_t)blk * 256 + tid] = scratch[tid] + scratch[256 + tid];
}

// ---------------------------------------------------------------------------
extern "C" void kernel_launch(void* const* d_in, const int* in_sizes, int n_in,
                              void* d_out, int out_size, void* d_ws, size_t ws_size,
                              hipStream_t stream)
{
    const float* hidden    = (const float*)d_in[0];
    const float* pos_table = (const float*)d_in[1];
    const float* Wpw       = (const float*)d_in[2];
    const float* Wpb       = (const float*)d_in[3];
    const float* W1w       = (const float*)d_in[4];
    const float* W1b       = (const float*)d_in[5];
    const float* W2w       = (const float*)d_in[6];
    const float* W2b       = (const float*)d_in[7];
    const float* qw        = (const float*)d_in[8];
    const float* qb        = (const float*)d_in[9];
    const int*   rpos      = (const int*)d_in[11];
    float* out = (float*)d_out;

    const int B = in_sizes[10];              // sessions (8192)

    // workspace layout (98816 B total)
    char* wsb = (char*)d_ws;
    float* ppK = (float*)wsb;                        // 65*128*4 = 33280
    u16* wb1   = (u16*)(wsb + 33280);                // 32768
    u16* wb2   = (u16*)(wsb + 33280 + 32768);        // 32768

    prep_kernel<<<193, 128, 0, stream>>>(pos_table, Wpw, Wpb, W2w,
                                         ppK, wb1, wb2);
    fused_kernel<<<B / 2, 512, 0, stream>>>(hidden, rpos, W1w, W1b, W2b, qw, qb,
                                            ppK, wb1, wb2, out);
}